// Round 2
// baseline (26573.630 us; speedup 1.0000x reference)
//
#include <hip/hip_runtime.h>
#include <hip/hip_bf16.h>

#define T_STEPS 4096
#define RES     4096
#define NIN     64
#define NOUT    32
#define NWG     256

typedef unsigned long long ull;

// ---------------------------------------------------------------------------
// Persistent recurrence kernel, PLAIN launch (grid=256=CU count, 1 WG/CU by
// __launch_bounds__(256,1) -> guaranteed co-resident; flag-based grid barrier).
// Wave wv owns rows r0..r0+3; each thread holds 256 f32 of W in VGPRs.
// x exchange: sc1 (agent) stores into a fresh row of the f32 history Xf[t],
// consumers use PLAIN cached loads (address never touched before -> no stale
// L1/L2 possible; per-XCD L2 then serves the other 31 WGs on that XCD).
// ---------------------------------------------------------------------------
__global__ __launch_bounds__(256, 1)
void esn_recur(const float* __restrict__ inp,
               const float* __restrict__ Win,
               const float* __restrict__ W,
               int*   __restrict__ flags,   // [256], zeroed => "x[0] published"
               float* __restrict__ Xf)      // [T][RES] f32; row 0 pre-zeroed
{
    const int g    = blockIdx.x;
    const int tid  = threadIdx.x;
    const int wv   = tid >> 6;
    const int lane = tid & 63;
    const int r0   = g * 16 + wv * 4;

    __shared__ float xs[RES];                 // 16 KiB staged x[t-1]

    // ---- W fragment into registers (once; reused for 4095 steps) ----------
    float w[4][64];
#pragma unroll
    for (int i = 0; i < 4; ++i) {
        const float* Wr = W + (size_t)(r0 + i) * RES + 2 * lane;
#pragma unroll
        for (int c1 = 0; c1 < 32; ++c1) {
            float2 v = *(const float2*)(Wr + 128 * c1);
            w[i][2 * c1]     = v.x;
            w[i][2 * c1 + 1] = v.y;
        }
    }
    float win[4];
#pragma unroll
    for (int i = 0; i < 4; ++i)
        win[i] = Win[(size_t)(r0 + i) * NIN + lane];

    float u = inp[NIN + lane];                // u for t=1

    for (int t = 1; t < T_STEPS; ++t) {
        // ---- grid barrier: all WGs published x[t-1] ------------------------
        if (wv == 0) {
            const int  want = t - 1;
            const ull* fp   = (const ull*)flags;    // 2 flags per 8B word
            for (;;) {
                ull q0 = __hip_atomic_load(fp + lane,      __ATOMIC_RELAXED, __HIP_MEMORY_SCOPE_AGENT);
                ull q1 = __hip_atomic_load(fp + 64 + lane, __ATOMIC_RELAXED, __HIP_MEMORY_SCOPE_AGENT);
                int ok = ((int)q0 >= want) & ((int)(q0 >> 32) >= want) &
                         ((int)q1 >= want) & ((int)(q1 >> 32) >= want);
                if (__all(ok)) break;
            }
        }
        __syncthreads();

        // ---- stage x[t-1] into LDS (plain loads; fresh address each step) --
        const float* xrow = Xf + (size_t)(t - 1) * RES;
        asm volatile("" : "+v"(xrow));        // don't hoist loads above the spin
        {
            const float4* s4 = (const float4*)xrow;
            float4*       d4 = (float4*)xs;
#pragma unroll
            for (int k = 0; k < 4; ++k)       // 256 thr x 4 x 16B, coalesced
                d4[tid + 256 * k] = s4[tid + 256 * k];
        }

        float ucur = u;
        if (t + 1 < T_STEPS) u = inp[(size_t)(t + 1) * NIN + lane];

        __syncthreads();

        // ---- a = W_in u_t + W x_{t-1} (4 rows/wave) ------------------------
        float a0 = win[0] * ucur, a1 = win[1] * ucur,
              a2 = win[2] * ucur, a3 = win[3] * ucur;
#pragma unroll
        for (int c1 = 0; c1 < 32; ++c1) {
            float xa = xs[2 * lane + 128 * c1];
            float xb = xs[2 * lane + 128 * c1 + 1];
            a0 += w[0][2 * c1] * xa + w[0][2 * c1 + 1] * xb;
            a1 += w[1][2 * c1] * xa + w[1][2 * c1 + 1] * xb;
            a2 += w[2][2 * c1] * xa + w[2][2 * c1 + 1] * xb;
            a3 += w[3][2 * c1] * xa + w[3][2 * c1 + 1] * xb;
        }
#pragma unroll
        for (int off = 32; off > 0; off >>= 1) {
            a0 += __shfl_xor(a0, off, 64);
            a1 += __shfl_xor(a1, off, 64);
            a2 += __shfl_xor(a2, off, 64);
            a3 += __shfl_xor(a3, off, 64);
        }

        if (lane < 4) {
            float s  = (lane == 0) ? a0 : (lane == 1) ? a1 : (lane == 2) ? a2 : a3;
            float xn = tanhf(s);
            // publish row (sc1 -> LLC) so other XCDs' plain loads see it
            __hip_atomic_store(Xf + (size_t)t * RES + r0 + lane, xn,
                               __ATOMIC_RELAXED, __HIP_MEMORY_SCOPE_AGENT);
        }
        // drain this wave's sc1 stores to the coherence point before the flag
        asm volatile("s_waitcnt vmcnt(0)" ::: "memory");
        __syncthreads();
        if (tid == 0)
            __hip_atomic_store(flags + g, t, __ATOMIC_RELAXED, __HIP_MEMORY_SCOPE_AGENT);
    }
}

// ---------------------------------------------------------------------------
// Readout: out[T,32] = Xf @ W_out. 2 t-rows per block, 2048 blocks.
// ---------------------------------------------------------------------------
__global__ __launch_bounds__(256)
void esn_out(const float* __restrict__ Xf,
             const float* __restrict__ Wout,
             float* __restrict__ out)
{
    __shared__ float xs[2 * RES];             // 32 KiB
    __shared__ float red[2][8][32];
    const int tid = threadIdx.x;
    const int t0  = blockIdx.x * 2;

    const float4* s4 = (const float4*)(Xf + (size_t)t0 * RES);
    float4*       d4 = (float4*)xs;
    for (int i = tid; i < 2 * RES / 4; i += 256)
        d4[i] = s4[i];
    __syncthreads();

    const int o  = tid & 31;
    const int sg = tid >> 5;                  // 8 segments of 512
    float acc0 = 0.f, acc1 = 0.f;
    const int rbeg = sg * 512;
    for (int r = rbeg; r < rbeg + 512; ++r) {
        float wv = Wout[(size_t)r * NOUT + o];
        acc0 += xs[r] * wv;
        acc1 += xs[RES + r] * wv;
    }
    red[0][sg][o] = acc0;
    red[1][sg][o] = acc1;
    __syncthreads();

    if (tid < 64) {
        const int h = tid >> 5, oo = tid & 31;
        float s = 0.f;
#pragma unroll
        for (int k = 0; k < 8; ++k) s += red[h][k][oo];
        out[(size_t)(t0 + h) * NOUT + oo] = s;
    }
}

// ---------------------------------------------------------------------------
extern "C" void kernel_launch(void* const* d_in, const int* in_sizes, int n_in,
                              void* d_out, int out_size, void* d_ws, size_t ws_size,
                              hipStream_t stream)
{
    const float* inputs = (const float*)d_in[0];   // [T, 64]
    const float* W_in   = (const float*)d_in[1];   // [RES, 64]
    const float* W      = (const float*)d_in[2];   // [RES, RES]
    const float* W_out  = (const float*)d_in[3];   // [RES, 32]
    float* out = (float*)d_out;                    // [T, 32]

    char*  ws    = (char*)d_ws;
    int*   flags = (int*)ws;                       // 1 KiB (padded to 4 KiB)
    float* Xf    = (float*)(ws + 4096);            // 64 MiB f32 history

    // Replay-safe init (ws is NOT re-poisoned between graph replays).
    hipMemsetAsync(flags, 0, NWG * sizeof(int), stream);
    hipMemsetAsync(Xf, 0, RES * sizeof(float), stream);   // x[0] = 0

    esn_recur<<<dim3(NWG), dim3(256), 0, stream>>>(inputs, W_in, W, flags, Xf);
    esn_out<<<dim3(T_STEPS / 2), dim3(256), 0, stream>>>(Xf, W_out, out);
}